// Round 9
// baseline (305.243 us; speedup 1.0000x reference)
//
#include <hip/hip_runtime.h>

#define POOL 14
#define IMG_H 128
#define IMG_W 128
#define IMG_C 1024
#define NROI 256
#define NSLICE 8                 // channel slices == XCDs
#define SLICE_C (IMG_C / NSLICE) // 128 channels per slice

typedef __attribute__((ext_vector_type(2))) float float2v;

__global__ __launch_bounds__(256) void roi_resize_kernel(
    const float* __restrict__ img,    // fp32, [128][128][1024]
    const float* __restrict__ rois,   // fp32, [256][4]
    float* __restrict__ out)          // fp32, [256][14][14][1024]
{
    // Channel-slice x ROI blocking.
    // block d = r*8 + s  ->  XCD = d%8 = s  (measured d%8->XCD mapping).
    // XCD s reads ONLY channels [s*128, s*128+128) of every gathered
    // pixel-row: each img byte is fetched by exactly ONE XCD (zero
    // cross-XCD duplication), per-XCD gather footprint = 67MB/8 = 8.4MB.
    const int d = blockIdx.x;
    const int s = d & 7;                       // channel slice / XCD
    const int r = d >> 3;                      // ROI index
    const int lane = threadIdx.x & 63;
    const int wv   = threadIdx.x >> 6;         // 4 waves: 4 pixels in parallel

    // ROI params (uniform across the block)
    const int x1 = (int)rois[r * 4 + 0];
    const int y1 = (int)rois[r * 4 + 1];
    const int x2 = (int)rois[r * 4 + 2];
    const int y2 = (int)rois[r * 4 + 3];
    const int h = y2 - y1;
    const int w = x2 - x1;
    // Hoisted; bitwise identical to reference's  i * (h / 14.0f)
    const float hdiv = (float)h / (float)POOL;
    const float wdiv = (float)w / (float)POOL;

    const int cofs = s * SLICE_C + lane * 2;   // 2 channels per lane, 8B loads
    const float* imgc = img + cofs;
    float* outc = out + (size_t)r * (POOL * POOL) * IMG_C + cofs;

    // 196 pixels = 49 iterations x 4 waves
    for (int it = 0; it < 49; ++it) {
        const int p = it * 4 + wv;             // pixel 0..195 (wave-uniform)
        const int i = p / POOL;
        const int j = p - i * POOL;

        const float src_y = (float)i * hdiv;
        const float src_x = (float)j * wdiv;
        const int y0 = (int)floorf(src_y);
        const int x0 = (int)floorf(src_x);
        const float fy = src_y - (float)y0;
        const float fx = src_x - (float)x0;
        const int y1i = min(y0 + 1, h - 1);
        const int x1i = min(x0 + 1, w - 1);
        const int ay0 = min(max(y1 + y0,  0), IMG_H - 1);
        const int ay1 = min(max(y1 + y1i, 0), IMG_H - 1);
        const int ax0 = min(max(x1 + x0,  0), IMG_W - 1);
        const int ax1 = min(max(x1 + x1i, 0), IMG_W - 1);

        // Each corner load: 64 lanes x 8B = one contiguous 512B segment.
        const float2v v00 = *(const float2v*)(imgc + (size_t)(ay0 * IMG_W + ax0) * IMG_C);
        const float2v v01 = *(const float2v*)(imgc + (size_t)(ay0 * IMG_W + ax1) * IMG_C);
        const float2v v10 = *(const float2v*)(imgc + (size_t)(ay1 * IMG_W + ax0) * IMG_C);
        const float2v v11 = *(const float2v*)(imgc + (size_t)(ay1 * IMG_W + ax1) * IMG_C);

        float2v o;
        #pragma unroll
        for (int k = 0; k < 2; ++k) {
            const float top = v00[k] + (v01[k] - v00[k]) * fx;
            const float bot = v10[k] + (v11[k] - v10[k]) * fx;
            o[k] = top + (bot - top) * fy;
        }
        // Streaming output, never re-read: non-temporal keeps L2/L3 for the gather set.
        __builtin_nontemporal_store(o, (float2v*)(outc + (size_t)p * IMG_C));
    }
}

extern "C" void kernel_launch(void* const* d_in, const int* in_sizes, int n_in,
                              void* d_out, int out_size, void* d_ws, size_t ws_size,
                              hipStream_t stream) {
    const float* img  = (const float*)d_in[0];
    const float* rois = (const float*)d_in[1];
    float* out = (float*)d_out;

    const int blocks = NROI * NSLICE;          // 2048: one (roi, channel-slice) each
    roi_resize_kernel<<<blocks, 256, 0, stream>>>(img, rois, out);
}